// Round 10
// baseline (47.689 us; speedup 1.0000x reference)
//
#include <hip/hip_runtime.h>
#include <math.h>

#define NM 16   // modes
#define NL 6    // layers
#define NW 15   // beamsplitters per layer
#define S2H 2.0f  // sqrt(2*hbar)
#define TILES 4  // 32-sample MFMA tiles per wave

typedef float v4f __attribute__((ext_vector_type(4)));
typedef short bf16x8 __attribute__((ext_vector_type(8)));
typedef float f32x16 __attribute__((ext_vector_type(16)));

// ws layout:
//   ushort wfrag[64][8]  at byte 0      (1 KB)  — MFMA W-fragment
//   float  bias[32]      at float 256   (byte 1024)

__device__ __forceinline__ unsigned short f2bf(float f) {
    union { float f; unsigned int u; } v; v.f = f;
    unsigned int r = (v.u + 0x7fffu + ((v.u >> 16) & 1u)) >> 16;   // RNE
    return (unsigned short)r;
}

__global__ __launch_bounds__(640) void cv_precompute(
    const float* __restrict__ disp,   // [2][NL][NM][2]
    const float* __restrict__ sq,     // [2][NL][NM][2]
    const float* __restrict__ bs,     // [2][NL][NW][2]
    float* __restrict__ ws)
{
    __shared__ float dxc[2][NL][NM], dpc[2][NL][NM];
    __shared__ float s00[2][NL][NM], s01[2][NL][NM], s11[2][NL][NM];
    __shared__ float bct[2][NL][NW], bcs[2][NL][NW], bss[2][NL][NW];

    int t = threadIdx.x;
    // Phase 1: parallel transcendental precompute into LDS
    if (t < 192) {
        int c = t / 96, rem = t % 96, l = rem / NM, n = rem % NM;
        float a  = disp[((c*NL + l)*NM + n)*2 + 0];
        float ph = disp[((c*NL + l)*NM + n)*2 + 1];
        dxc[c][l][n] = S2H * a * cosf(ph);
        dpc[c][l][n] = S2H * a * sinf(ph);
    } else if (t < 384) {
        int i = t - 192;
        int c = i / 96, rem = i % 96, l = rem / NM, n = rem % NM;
        float r  = fabsf(sq[((c*NL + l)*NM + n)*2 + 0]);
        float ph = sq[((c*NL + l)*NM + n)*2 + 1];
        float ch = coshf(r), sh = sinhf(r);
        float cp = cosf(ph), sp = sinf(ph);
        s00[c][l][n] = ch - cp*sh;
        s01[c][l][n] = -sp*sh;
        s11[c][l][n] = ch + cp*sh;
    } else if (t < 564) {
        int i = t - 384;
        int c = i / 90, rem = i % 90, l = rem / NW, w = rem % NW;
        float z  = bs[((c*NL + l)*NW + w)*2 + 0];
        float ph = bs[((c*NL + l)*NW + w)*2 + 1];
        float th = 1.0f / (1.0f + expf(-z));
        float ct = cosf(th), st = sinf(th);
        bct[c][l][w] = ct;
        bcs[c][l][w] = cosf(ph) * st;
        bss[c][l][w] = sinf(ph) * st;
    }
    __syncthreads();

    // Phase 2: 34 threads propagate basis vectors (pure FMA chain).
    // col < 16: linear column (no displacement). col == 16: bias (zero input
    // WITH displacement). Affine map F(x)=Mx+c decomposes exactly so.
    if (t >= 34) return;
    int c = t / 17;
    int col = t % 17;
    bool isBias = (col == NM);

    float mx[NM], mp[NM];
    #pragma unroll
    for (int n = 0; n < NM; ++n) { mx[n] = 0.f; mp[n] = 0.f; }
    if (!isBias) mx[col] = S2H;   // mx = S2H * x

    for (int l = 0; l < NL; ++l) {
        if (isBias) {
            #pragma unroll
            for (int n = 0; n < NM; ++n) { mx[n] += dxc[c][l][n]; mp[n] += dpc[c][l][n]; }
        }
        #pragma unroll
        for (int n = 0; n < NM; ++n) {
            float a = s00[c][l][n], b = s01[c][l][n], d = s11[c][l][n];
            float nx  = a*mx[n] + b*mp[n];
            float npp = b*mx[n] + d*mp[n];
            mx[n] = nx; mp[n] = npp;
        }
        #pragma unroll
        for (int w = 0; w < NW; ++w) {
            float ct = bct[c][l][w], cst = bcs[c][l][w], sst = bss[c][l][w];
            float x1 = mx[w], x2 = mx[w+1], p1 = mp[w], p2 = mp[w+1];
            mx[w]   = ct*x1  - cst*x2 - sst*p2;
            mx[w+1] = cst*x1 + ct*x2  - sst*p1;
            mp[w]   = sst*x2 + ct*p1  - cst*p2;
            mp[w+1] = sst*x1 + cst*p1 + ct*p2;
        }
    }

    // Emit MFMA W-fragment (bf16) + f32 bias.
    // Fragment value at lane L, slot j = W[L&31][8*(L>>5)+j]; this thread
    // owns column k=col of W.  (Same bytes served as B[k][n]=W[n][k] in the
    // R8 orientation and as A[m][k]=W[m][k] in the current one.)
    ushort* bfp  = (ushort*)ws;
    float* biasp = ws + 256;
    if (!isBias) {
        #pragma unroll
        for (int n = 0; n < NM; ++n) {
            int row = 16*c + n;                       // output channel
            float val = (c == 0) ? mx[n] : mp[n];     // W[row][col]
            int lane = row + 32 * (col >> 3);
            int slot = col & 7;
            bfp[lane * 8 + slot] = f2bf(val);
        }
    } else {
        #pragma unroll
        for (int n = 0; n < NM; ++n)
            biasp[16*c + n] = (c == 0) ? mx[n] : mp[n];
    }
}

// MFMA apply, operand-swapped: D = W · X^T.
//   A = W fragment (lane L: channel m = L&31, k = 8*(L>>5)+j)  [1 KB, loaded once]
//   B = x fragment (lane L: sample  n = L&31, k = 8*(L>>5)+j)  [2 dwordx4/lane/tile]
//   D[m=channel][n=sample]: lane owns ONE SAMPLE, rows are channel quads
//     (r&3)+8*(r>>2)+4*kg  ->  4 direct dwordx4 stores to
//     out[sample*32 + {0,8,16,24} + 4*kg].  NO LDS, NO barriers — pure
//     straight-line 8 loads -> 4 MFMA -> 16 stores.  A wave's 4 stores per
//     tile cover each 64B line in 2 back-to-back instructions; normal
//     cached stores let L2 write-combine (the 7 TB/s fill-kernel path).
__global__ __launch_bounds__(256, 3) void cv_apply(
    const float* __restrict__ x,
    const float* __restrict__ ws,
    float* __restrict__ out,
    long long B)
{
    const int t = threadIdx.x;
    const int lane = t & 63;
    const int wave = t >> 6;
    const int s32 = lane & 31;                      // sample-within-tile / D col
    const int kg = lane >> 5;                       // k-group (0/1)

    const bf16x8 wfrag = *(const bf16x8*)((const ushort*)ws + lane * 8);

    // Per-lane bias for D rows: channel(r) = (r&3) + 8*(r>>2) + 4*kg
    const float* biasp = ws + 256;
    float bias16[16];
    #pragma unroll
    for (int r = 0; r < 16; ++r)
        bias16[r] = biasp[(r & 3) + 8 * (r >> 2) + 4 * kg];

    const long long wbase = ((long long)blockIdx.x * 4 + wave) * (32 * TILES);

    // ---- issue ALL x loads up front (8 dwordx4 per lane) ----
    float4 va[TILES][2];
    #pragma unroll
    for (int tt = 0; tt < TILES; ++tt) {
        const long long smp = wbase + tt * 32 + s32;
        if (smp < B) {
            const float4* xp = (const float4*)(x + smp * 16 + kg * 8);
            va[tt][0] = xp[0];
            va[tt][1] = xp[1];
        } else {
            va[tt][0] = make_float4(0.f, 0.f, 0.f, 0.f);
            va[tt][1] = make_float4(0.f, 0.f, 0.f, 0.f);
        }
    }

    // ---- per tile: convert, MFMA (bias in C), 4 direct stores ----
    #pragma unroll
    for (int tt = 0; tt < TILES; ++tt) {
        bf16x8 xf;
        xf[0] = (short)f2bf(va[tt][0].x); xf[1] = (short)f2bf(va[tt][0].y);
        xf[2] = (short)f2bf(va[tt][0].z); xf[3] = (short)f2bf(va[tt][0].w);
        xf[4] = (short)f2bf(va[tt][1].x); xf[5] = (short)f2bf(va[tt][1].y);
        xf[6] = (short)f2bf(va[tt][1].z); xf[7] = (short)f2bf(va[tt][1].w);

        f32x16 cin;
        #pragma unroll
        for (int r = 0; r < 16; ++r) cin[r] = bias16[r];

        f32x16 acc = __builtin_amdgcn_mfma_f32_32x32x16_bf16(wfrag, xf, cin, 0, 0, 0);

        const long long smp = wbase + tt * 32 + s32;
        if (smp < B) {
            float* op = out + smp * 32 + 4 * kg;
            #pragma unroll
            for (int g = 0; g < 4; ++g) {           // channel quads 0/8/16/24 (+4kg)
                v4f r4; r4[0] = acc[g*4+0]; r4[1] = acc[g*4+1];
                r4[2] = acc[g*4+2]; r4[3] = acc[g*4+3];
                *(v4f*)(op + g * 8) = r4;
            }
        }
    }
}

extern "C" void kernel_launch(void* const* d_in, const int* in_sizes, int n_in,
                              void* d_out, int out_size, void* d_ws, size_t ws_size,
                              hipStream_t stream) {
    const float* x    = (const float*)d_in[0];
    const float* disp = (const float*)d_in[1];
    const float* sq   = (const float*)d_in[2];
    const float* bs   = (const float*)d_in[3];
    float* ws  = (float*)d_ws;
    float* out = (float*)d_out;

    long long B = in_sizes[0] / NM;

    cv_precompute<<<1, 640, 0, stream>>>(disp, sq, bs, ws);

    long long per_block = 4LL * 32 * TILES;        // 512 samples
    int blocks = (int)((B + per_block - 1) / per_block);   // 2048 for B=1M
    cv_apply<<<blocks, 256, 0, stream>>>(x, ws, out, B);
}

// Round 11
// 44.454 us; speedup vs baseline: 1.0728x; 1.0728x over previous
//
#include <hip/hip_runtime.h>
#include <math.h>

#define NM 16   // modes
#define NL 6    // layers
#define NW 15   // beamsplitters per layer
#define S2H 2.0f  // sqrt(2*hbar)

typedef float v4f __attribute__((ext_vector_type(4)));
typedef short bf16x8 __attribute__((ext_vector_type(8)));
typedef float f32x16 __attribute__((ext_vector_type(16)));

// ws layout:
//   ushort wfrag[64][8]  at byte 0      (1 KB)  — MFMA B-fragment of W^T
//   float  bias[32]      at float 256   (byte 1024)

__device__ __forceinline__ unsigned short f2bf(float f) {
    union { float f; unsigned int u; } v; v.f = f;
    unsigned int r = (v.u + 0x7fffu + ((v.u >> 16) & 1u)) >> 16;   // RNE
    return (unsigned short)r;
}

__global__ __launch_bounds__(640) void cv_precompute(
    const float* __restrict__ disp,   // [2][NL][NM][2]
    const float* __restrict__ sq,     // [2][NL][NM][2]
    const float* __restrict__ bs,     // [2][NL][NW][2]
    float* __restrict__ ws)
{
    __shared__ float dxc[2][NL][NM], dpc[2][NL][NM];
    __shared__ float s00[2][NL][NM], s01[2][NL][NM], s11[2][NL][NM];
    __shared__ float bct[2][NL][NW], bcs[2][NL][NW], bss[2][NL][NW];

    int t = threadIdx.x;
    // Phase 1: parallel transcendental precompute into LDS
    if (t < 192) {
        int c = t / 96, rem = t % 96, l = rem / NM, n = rem % NM;
        float a  = disp[((c*NL + l)*NM + n)*2 + 0];
        float ph = disp[((c*NL + l)*NM + n)*2 + 1];
        dxc[c][l][n] = S2H * a * cosf(ph);
        dpc[c][l][n] = S2H * a * sinf(ph);
    } else if (t < 384) {
        int i = t - 192;
        int c = i / 96, rem = i % 96, l = rem / NM, n = rem % NM;
        float r  = fabsf(sq[((c*NL + l)*NM + n)*2 + 0]);
        float ph = sq[((c*NL + l)*NM + n)*2 + 1];
        float ch = coshf(r), sh = sinhf(r);
        float cp = cosf(ph), sp = sinf(ph);
        s00[c][l][n] = ch - cp*sh;
        s01[c][l][n] = -sp*sh;
        s11[c][l][n] = ch + cp*sh;
    } else if (t < 564) {
        int i = t - 384;
        int c = i / 90, rem = i % 90, l = rem / NW, w = rem % NW;
        float z  = bs[((c*NL + l)*NW + w)*2 + 0];
        float ph = bs[((c*NL + l)*NW + w)*2 + 1];
        float th = 1.0f / (1.0f + expf(-z));
        float ct = cosf(th), st = sinf(th);
        bct[c][l][w] = ct;
        bcs[c][l][w] = cosf(ph) * st;
        bss[c][l][w] = sinf(ph) * st;
    }
    __syncthreads();

    // Phase 2: 34 threads propagate basis vectors (pure FMA chain).
    // col < 16: linear column (no displacement). col == 16: bias (zero input
    // WITH displacement). Affine map F(x)=Mx+c decomposes exactly so.
    if (t >= 34) return;
    int c = t / 17;
    int col = t % 17;
    bool isBias = (col == NM);

    float mx[NM], mp[NM];
    #pragma unroll
    for (int n = 0; n < NM; ++n) { mx[n] = 0.f; mp[n] = 0.f; }
    if (!isBias) mx[col] = S2H;   // mx = S2H * x

    for (int l = 0; l < NL; ++l) {
        if (isBias) {
            #pragma unroll
            for (int n = 0; n < NM; ++n) { mx[n] += dxc[c][l][n]; mp[n] += dpc[c][l][n]; }
        }
        #pragma unroll
        for (int n = 0; n < NM; ++n) {
            float a = s00[c][l][n], b = s01[c][l][n], d = s11[c][l][n];
            float nx  = a*mx[n] + b*mp[n];
            float npp = b*mx[n] + d*mp[n];
            mx[n] = nx; mp[n] = npp;
        }
        #pragma unroll
        for (int w = 0; w < NW; ++w) {
            float ct = bct[c][l][w], cst = bcs[c][l][w], sst = bss[c][l][w];
            float x1 = mx[w], x2 = mx[w+1], p1 = mp[w], p2 = mp[w+1];
            mx[w]   = ct*x1  - cst*x2 - sst*p2;
            mx[w+1] = cst*x1 + ct*x2  - sst*p1;
            mp[w]   = sst*x2 + ct*p1  - cst*p2;
            mp[w+1] = sst*x1 + cst*p1 + ct*p2;
        }
    }

    // Emit MFMA B-fragment of W (bf16) + f32 bias.
    // B-frag (32x32x16): value at lane L, slot j = B[k=8*(L>>5)+j][n=L&31]
    //   = W[n][k];  this thread owns column k=col of W.
    ushort* bfp  = (ushort*)ws;
    float* biasp = ws + 256;
    if (!isBias) {
        #pragma unroll
        for (int n = 0; n < NM; ++n) {
            int row = 16*c + n;                       // output channel
            float val = (c == 0) ? mx[n] : mp[n];     // W[row][col]
            int lane = row + 32 * (col >> 3);
            int slot = col & 7;
            bfp[lane * 8 + slot] = f2bf(val);
        }
    } else {
        #pragma unroll
        for (int n = 0; n < NM; ++n)
            biasp[16*c + n] = (c == 0) ? mx[n] : mp[n];
    }
}

// MFMA apply: one 128-sample tile per 256-thread block, OCCUPANCY-MAXED.
// __launch_bounds__(256,8) caps VGPR at 64 -> 8 blocks/CU (32 waves/CU,
// 100% occupancy; LDS 16KB x 8 = 128KB of 160). Same verified structure
// as R8/R9 (best at 44.0): X=A-frag, W=B-frag, bias in MFMA C operand,
// LDS-staged transpose (conflict-free), lane-consecutive NT dwordx4 out.
// Single-variable probe: does doubling resident waves (deeper read+write
// queues per CU) lift the ~8 B/cyc/CU mixed-stream rate toward the
// copy-benchmark 10.2?
__global__ __launch_bounds__(256, 8) void cv_apply(
    const float* __restrict__ x,
    const float* __restrict__ ws,
    float* __restrict__ out,
    long long B)
{
    __shared__ float st[128 * 32];                  // 16 KB
    const int t = threadIdx.x;
    const int lane = t & 63;
    const int wave = t >> 6;
    const int n = lane & 31;                        // output channel / D col
    const int kg = lane >> 5;                       // k-group (0/1)

    const bf16x8 bfrag = *(const bf16x8*)((const ushort*)ws + lane * 8);
    const float  bn    = (ws + 256)[n];

    const long long b0 = (long long)blockIdx.x * 128;
    const long long row = b0 + wave * 32 + n;       // this lane's sample

    // A-fragment: 2 dwordx4 (dense: 2 instrs cover 2KB contiguous per wave)
    float4 va0, va1;
    if (row < B) {
        const float4* xp = (const float4*)(x + row * 16 + kg * 8);
        va0 = xp[0];
        va1 = xp[1];
    } else {
        va0 = make_float4(0.f, 0.f, 0.f, 0.f);
        va1 = make_float4(0.f, 0.f, 0.f, 0.f);
    }

    bf16x8 af;
    af[0] = (short)f2bf(va0.x); af[1] = (short)f2bf(va0.y);
    af[2] = (short)f2bf(va0.z); af[3] = (short)f2bf(va0.w);
    af[4] = (short)f2bf(va1.x); af[5] = (short)f2bf(va1.y);
    af[6] = (short)f2bf(va1.z); af[7] = (short)f2bf(va1.w);

    f32x16 cin;
    #pragma unroll
    for (int r = 0; r < 16; ++r) cin[r] = bn;       // bias in C operand

    f32x16 acc = __builtin_amdgcn_mfma_f32_32x32x16_bf16(af, bfrag, cin, 0, 0, 0);

    // Stage D to LDS (conflict-free: lanes n=0..31 hit banks 0..31)
    #pragma unroll
    for (int r = 0; r < 16; ++r) {
        int m = (r & 3) + 8 * (r >> 2) + 4 * kg;
        st[(wave * 32 + m) * 32 + n] = acc[r];
    }
    __syncthreads();

    // Coalesced NT store: 4 x 4KB-per-wave bursts, lane-consecutive float4
    v4f* __restrict__ op = (v4f*)(out + b0 * 32);
    const long long rem = B - b0;
    const long long u4max = (rem < 128 ? rem : 128) * 8;
    const float4* stv = (const float4*)st;
    #pragma unroll
    for (int i = 0; i < 4; ++i) {
        int u = i * 256 + t;
        if (u < u4max) {
            float4 v = stv[u];
            v4f r; r[0]=v.x; r[1]=v.y; r[2]=v.z; r[3]=v.w;
            __builtin_nontemporal_store(r, op + u);
        }
    }
}

extern "C" void kernel_launch(void* const* d_in, const int* in_sizes, int n_in,
                              void* d_out, int out_size, void* d_ws, size_t ws_size,
                              hipStream_t stream) {
    const float* x    = (const float*)d_in[0];
    const float* disp = (const float*)d_in[1];
    const float* sq   = (const float*)d_in[2];
    const float* bs   = (const float*)d_in[3];
    float* ws  = (float*)d_ws;
    float* out = (float*)d_out;

    long long B = in_sizes[0] / NM;

    cv_precompute<<<1, 640, 0, stream>>>(disp, sq, bs, ws);

    int blocks = (int)((B + 127) / 128);            // 8192 for B=1M
    cv_apply<<<blocks, 256, 0, stream>>>(x, ws, out, B);
}